// Round 5
// baseline (383.412 us; speedup 1.0000x reference)
//
#include <hip/hip_runtime.h>
#include <hip/hip_bf16.h>
#include <stdint.h>

// ---------------------------------------------------------------------------
// TensorizedGRU: m[b,l] = sum_{j,k} s[b,j] x[b,k] W[l,j,k]  (l in [0,256): W1||W2)
// R14 = R12 (133.3us, MfmaUtil 47.5, the best config) + deep B-prefetch:
//  - R13 post-mortem: 32x32 path spilled (VGPR 128, WRITE 2x = scratch) and
//    paid ~190 VALU/chunk in accvgpr moves -> round x1.57 as the additive
//    issue model predicts. Reverted.
//  - R12 stall audit: 653cyc round = 310 MFMA + ~170 issue + ~340 STALL.
//    Every Wt byte is read once by one block -> B-loads are ~900cyc HBM
//    misses; 1-chunk-ahead prefetch covers only ~330cyc. Fix: prefetch
//    3 chunks ahead (ring of 4).
//  - Enabler: prep writes Wt fragments in EXACT consumption order
//    (n16 -> ks -> q -> jl -> kst), so the B pointer is one monotone
//    vo += 2048/chunk across q boundaries; ring indices are compile-time
//    (jj unroll 4). Tail overshoot (<=6KB) lands in the 2MB ws gap. A-frags
//    still reloaded per q (4 exposed L2 latencies/wave, ~1200cyc total).
// ws layout:
//   Wt   bf16 [256][65536]  @ 0          (33,554,432 B)  consumption-ordered
//   x_bf bf16 [4096][256]   @ 32MiB+2MiB ( 2,097,152 B)
//   Mpart f32 [8][4096][256]@ +2MiB      (33,554,432 B)
// ---------------------------------------------------------------------------

typedef short bf8 __attribute__((ext_vector_type(8)));   // 8 bf16 = 4 VGPRs
typedef float f32x4 __attribute__((ext_vector_type(4)));

static constexpr size_t WT_OFF  = 0;
static constexpr size_t XBF_OFF = 33554432 + 2097152;
static constexpr size_t MP_OFF  = XBF_OFF + 2097152;

// round-to-nearest-even f32 -> bf16 (finite inputs only)
__device__ __forceinline__ unsigned f2bf(float f) {
    unsigned u = __builtin_bit_cast(unsigned, f);
    return (u + 0x7fffu + ((u >> 16) & 1u)) >> 16;
}
__device__ __forceinline__ unsigned pack2bf(float a, float b) {
    return f2bf(a) | (f2bf(b) << 16);
}

// ---------------- prep: consumption-ordered Wt (wave-per-frag) + x cast -----
// Fragment id f in [0, 32768), 1KB each:
//   f = ((((n16*8 + ks)*4 + q)*32 + jl)*2 + kst)
//   kchunk = (ks*32 + jl)*4 + q   (64-float K-chunk index)
// Frag content (16x16x32 B-operand): lane l holds
//   W[n16*16 + (l&15)][kchunk*64 + kst*32 + (l>>4)*8 .. +8) as 8 bf16.
// Blocks 0..8191: 4 waves/block, wave w makes frag f = bx*4 + w.
// Blocks 8192..9215: x = in0||in1 -> bf16 (row-major [4096][256]).
__global__ void prep_wx(const float* __restrict__ W1, const float* __restrict__ W2,
                        const float* __restrict__ in0, const float* __restrict__ in1,
                        uint4* __restrict__ Wt, unsigned* __restrict__ x_bf) {
    int bx = blockIdx.x;
    if (bx < 8192) {
        const int tid  = threadIdx.x;
        const int lane = tid & 63, wave = tid >> 6;
        const unsigned f = bx * 4 + wave;
        const unsigned n16 = f >> 11;
        const unsigned r2  = f & 2047u;
        const unsigned ks  = r2 >> 8;
        const unsigned rem = r2 & 255u;
        const unsigned q   = rem >> 6;
        const unsigned jl  = (rem >> 1) & 31u;
        const unsigned kst = rem & 1u;
        const unsigned kchunk = (ks * 32 + jl) * 4 + q;
        const unsigned n = n16 * 16 + (lane & 15);
        const unsigned K = kchunk * 64 + kst * 32 + (lane >> 4) * 8;
        const float* src = (n < 128 ? W1 + ((size_t)n << 16)
                                    : W2 + ((size_t)(n - 128) << 16)) + K;
        float4 a = ((const float4*)src)[0];
        float4 b = ((const float4*)src)[1];
        uint4 o;
        o.x = pack2bf(a.x, a.y); o.y = pack2bf(a.z, a.w);
        o.z = pack2bf(b.x, b.y); o.w = pack2bf(b.z, b.w);
        Wt[(size_t)f * 64 + lane] = o;        // contiguous 1KB per wave
    } else {
        unsigned v = (bx - 8192) * 256 + threadIdx.x; // 262,144 units of 4 elems
        unsigned b = v >> 6;
        unsigned j4 = (v & 63u) * 4u;
        const float* src = (j4 < 128) ? (in0 + (size_t)b * 128 + j4)
                                      : (in1 + (size_t)b * 128 + (j4 - 128));
        float4 a = *(const float4*)src;
        uint2 o;
        o.x = pack2bf(a.x, a.y);
        o.y = pack2bf(a.z, a.w);
        ((uint2*)x_bf)[v] = o;
    }
}

// ---------------- main GEMM: 128x128 tile, split-K=8, barrier-free ----------
// grid 512: ks = bx&7 (XCD-pinned), nt = (bx>>3)&1, mt = bx>>4 (0..31).
// block 256 = 4 waves; wave w owns n-cols [w*32, w*32+32), all 128 m-rows.
__launch_bounds__(256, 2)
__global__ void gemm_p(const unsigned char* __restrict__ Wt,
                       const float* __restrict__ st0, const float* __restrict__ st1,
                       const __hip_bfloat16* __restrict__ x_bf,
                       float* __restrict__ Mpart) {
    const int bx = blockIdx.x;
    const int ks = bx & 7;                  // split-K slice, pinned per XCD
    const int nt = (bx >> 3) & 1;
    const int mt = bx >> 4;
    const int b0 = mt << 7, n0 = nt << 7;
    const int tid  = threadIdx.x;
    const int lane = tid & 63, wave = tid >> 6;
    const int l15 = lane & 15, l4 = lane >> 4;

    // s tile: [32 j][132 r] f32 (pad to 132 -> broadcast-clean)
    __shared__ __align__(16) float Sl[32 * 132];
    for (int idx = tid; idx < 4096; idx += 256) {
        int r = idx >> 5, j = idx & 31;
        int jg = ks * 32 + j;
        float v = (jg < 128) ? st0[(size_t)(b0 + r) * 128 + jg]
                             : st1[(size_t)(b0 + r) * 128 + (jg - 128)];
        Sl[j * 132 + r] = v;
    }
    __syncthreads();                        // the ONLY barrier

    // Wave-uniform Wt slice bases in SGPRs: n16(nf) = nt*8 + wave*2 + nf.
    const int n16_0 = __builtin_amdgcn_readfirstlane(nt * 8 + wave * 2 + 0);
    const int n16_1 = __builtin_amdgcn_readfirstlane(nt * 8 + wave * 2 + 1);
    const unsigned char* wb0 = Wt + ((size_t)n16_0 << 21);
    const unsigned char* wb1 = Wt + ((size_t)n16_1 << 21);

    f32x4 racc[8][2];
    #pragma unroll
    for (int mf = 0; mf < 8; ++mf)
        #pragma unroll
        for (int nf = 0; nf < 2; ++nf)
            racc[mf][nf] = (f32x4){0.f, 0.f, 0.f, 0.f};
    const f32x4 zacc = (f32x4){0.f, 0.f, 0.f, 0.f};

    bf8 a[8][2];                            // x A-frags, reloaded per quadrant
    bf8 buf[4][2][2];                       // [slot][nf][kst] prefetch ring

    // Monotone within-slice byte offset (consumption-ordered Wt):
    // chunk c -> vo = lane*16 + ks*262144 + c*2048; kst*1024 in load imm.
    unsigned vo = (unsigned)lane * 16u + (unsigned)ks * 262144u;

    // warm-up: chunks 0..2 into ring slots 0..2
    #pragma unroll
    for (int w = 0; w < 3; ++w) {
        buf[w][0][0] = *(const bf8*)(wb0 + vo);
        buf[w][0][1] = *(const bf8*)(wb0 + vo + 1024);
        buf[w][1][0] = *(const bf8*)(wb1 + vo);
        buf[w][1][1] = *(const bf8*)(wb1 + vo + 1024);
        vo += 2048;
    }
    // vo now points at chunk 3 (first prefetch target)

    for (int q = 0; q < 4; ++q) {
        // A-frags for this x-quadrant (x_bf row-major, L2-resident)
        #pragma unroll
        for (int mf = 0; mf < 8; ++mf) {
            const __hip_bfloat16* xp =
                x_bf + (size_t)((b0 + mf * 16 + l15) * 256 + q * 64 + l4 * 8);
            a[mf][0] = *(const bf8*)(xp);
            a[mf][1] = *(const bf8*)(xp + 32);
        }

        const float* svp = Sl + l4 * 4;      // s broadcast ptr, +132/chunk

        for (int jb = 0; jb < 8; ++jb) {
            #pragma unroll
            for (int jj = 0; jj < 4; ++jj) {
                // prefetch chunk c+3 into slot (jj+3)&3 (tail overshoots
                // <=6KB into the 2MB ws gap after Wt: valid, discarded)
                {
                    const int ps = (jj + 3) & 3;
                    buf[ps][0][0] = *(const bf8*)(wb0 + vo);
                    buf[ps][0][1] = *(const bf8*)(wb0 + vo + 1024);
                    buf[ps][1][0] = *(const bf8*)(wb1 + vo);
                    buf[ps][1][1] = *(const bf8*)(wb1 + vo + 1024);
                    vo += 2048;
                }
                // s broadcast values for this j (imm-folded mf*64B)
                f32x4 sv[8];
                #pragma unroll
                for (int mf = 0; mf < 8; ++mf)
                    sv[mf] = *(const f32x4*)(svp + mf * 16);
                svp += 132;
                // 32 MFMA + f32 scale-accumulate, consuming ring slot jj
                #pragma unroll
                for (int nf = 0; nf < 2; ++nf) {
                    bf8 bf0 = buf[jj][nf][0];
                    bf8 bf1 = buf[jj][nf][1];
                    #pragma unroll
                    for (int mf = 0; mf < 8; ++mf) {
                        f32x4 m0 = __builtin_amdgcn_mfma_f32_16x16x32_bf16(a[mf][0], bf0, zacc, 0, 0, 0);
                        m0 = __builtin_amdgcn_mfma_f32_16x16x32_bf16(a[mf][1], bf1, m0, 0, 0, 0);
                        racc[mf][nf] += sv[mf] * m0;
                    }
                }
            }
        }
    }

    // split-K partial stores (regular stores: producer->consumer coherence)
    float* mp = Mpart + ((size_t)ks << 20);
    #pragma unroll
    for (int mf = 0; mf < 8; ++mf)
        #pragma unroll
        for (int nf = 0; nf < 2; ++nf) {
            int b = b0 + mf * 16 + l4 * 4;
            int n = n0 + wave * 32 + nf * 16 + l15;
            #pragma unroll
            for (int r = 0; r < 4; ++r)
                mp[(size_t)(b + r) * 256 + n] = racc[mf][nf][r];
        }
}

// ---------------- epilogue: reduce split-K, s@W3, activations, blend --------
__global__ void epilogue(const float* __restrict__ st0, const float* __restrict__ st1,
                         const float* __restrict__ b1, const float* __restrict__ b2,
                         const float* __restrict__ W3, const float* __restrict__ Mpart,
                         float* __restrict__ out) {
    const int tid = threadIdx.x;
    const int h = tid & 127, rg = tid >> 7;          // rg in {0,1}
    const int bbase = blockIdx.x * 4;                // 4 rows per block
    __shared__ float srow[4][256];
    #pragma unroll
    for (int i = 0; i < 4; ++i) {
        int idx = i * 256 + tid;
        int r = idx >> 8, j = idx & 255;
        float v = (j < 128) ? st0[(size_t)(bbase + r) * 128 + j]
                            : st1[(size_t)(bbase + r) * 128 + (j - 128)];
        srow[r][j] = v;
    }
    __syncthreads();
    float acc0 = 0.f, acc1 = 0.f;
    #pragma unroll 8
    for (int j = 0; j < 256; ++j) {
        float w = W3[j * 128 + h];
        acc0 += srow[rg][j] * w;
        acc1 += srow[rg + 2][j] * w;
    }
    float accs[2] = {acc0, acc1};
    float bb1 = b1[h], bb2 = b2[h];
    #pragma unroll
    for (int i = 0; i < 2; ++i) {
        int b = bbase + rg + i * 2;
        float m1 = 0.f, m2 = 0.f;
        #pragma unroll
        for (int k = 0; k < 8; ++k) {
            m1 += Mpart[((size_t)k << 20) + (size_t)b * 256 + h];
            m2 += Mpart[((size_t)k << 20) + (size_t)b * 256 + 128 + h];
        }
        float u = 1.0f / (1.0f + expf(-(m2 + bb2)));
        float t = tanhf(m1 + bb1);
        out[(size_t)b * 128 + h] = u * t + (1.0f - u) * accs[i];
    }
}

extern "C" void kernel_launch(void* const* d_in, const int* in_sizes, int n_in,
                              void* d_out, int out_size, void* d_ws, size_t ws_size,
                              hipStream_t stream) {
    const float* in0 = (const float*)d_in[0];
    const float* in1 = (const float*)d_in[1];
    const float* st0 = (const float*)d_in[2];
    const float* st1 = (const float*)d_in[3];
    const float* W1  = (const float*)d_in[4];
    const float* b1  = (const float*)d_in[5];
    const float* W2  = (const float*)d_in[6];
    const float* b2  = (const float*)d_in[7];
    const float* W3  = (const float*)d_in[8];
    float* out = (float*)d_out;
    char* ws = (char*)d_ws;

    unsigned char* Wt   = (unsigned char*)(ws + WT_OFF);
    unsigned*      x_bf = (unsigned*)(ws + XBF_OFF);
    float*         Mp   = (float*)(ws + MP_OFF);

    prep_wx<<<9216, 256, 0, stream>>>(W1, W2, in0, in1, (uint4*)Wt, x_bf);
    gemm_p<<<512, 256, 0, stream>>>(Wt, st0, st1, (const __hip_bfloat16*)x_bf, Mp);
    epilogue<<<1024, 256, 0, stream>>>(st0, st1, b1, b2, W3, Mp, out);
}

// Round 7
// 258.767 us; speedup vs baseline: 1.4817x; 1.4817x over previous
//
#include <hip/hip_runtime.h>
#include <hip/hip_bf16.h>
#include <stdint.h>

// ---------------------------------------------------------------------------
// TensorizedGRU: m[b,l] = sum_{j,k} s[b,j] x[b,k] W[l,j,k]  (l in [0,256): W1||W2)
// R16 = R15's distance-1 MFMA->fma pipeline, re-encoded crash-safe:
//  - R15 (m[p&1] array + unrolled loop) core-dumped with no counters; only
//    delta vs known-good R12 was that loop encoding. R16 expresses the SAME
//    instruction reordering as a flat macro sequence over named registers
//    mA/mB (no arrays, no loop-var indexing) -> code shape ~= R12 + reorder.
//  - Theory (untested by R15's crash): R12's `racc += sv*m0` reads the MFMA
//    result immediately -> ~40cyc result-latency stall x16 pairs/chunk
//    (~600cyc of the 2494cyc round). Deferring each fma by one pair hides it.
//    Arithmetic is bit-identical (same chains, same accumulation order).
//  - Everything else byte-identical to R12 (prep layout, vo walk, stores,
//    s f32 [32][132], grid 512, split-K 8, 2 blocks/CU).
// ws layout:
//   Wt   bf16 [256][65536]  @ 0          (33,554,432 B)  fragment-ordered
//   x_bf bf16 [4096][256]   @ 32MiB+2MiB ( 2,097,152 B)
//   Mpart f32 [8][4096][256]@ +2MiB      (33,554,432 B)
// ---------------------------------------------------------------------------

typedef short bf8 __attribute__((ext_vector_type(8)));   // 8 bf16 = 4 VGPRs
typedef float f32x4 __attribute__((ext_vector_type(4)));

static constexpr size_t WT_OFF  = 0;
static constexpr size_t XBF_OFF = 33554432 + 2097152;
static constexpr size_t MP_OFF  = XBF_OFF + 2097152;

// round-to-nearest-even f32 -> bf16 (finite inputs only)
__device__ __forceinline__ unsigned f2bf(float f) {
    unsigned u = __builtin_bit_cast(unsigned, f);
    return (u + 0x7fffu + ((u >> 16) & 1u)) >> 16;
}
__device__ __forceinline__ unsigned pack2bf(float a, float b) {
    return f2bf(a) | (f2bf(b) << 16);
}

// ---------------- prep: fragment-ordered Wt (wave-per-frag) + x cast --------
// Fragment f = ((n16*1024 + kchunk)*2 + kst), f in [0, 32768).
// Blocks 0..8191: 4 waves/block, wave w makes frag f = bx*4 + w.
// Blocks 8192..9215: x = in0||in1 -> bf16 (row-major [4096][256]).
__global__ void prep_wx(const float* __restrict__ W1, const float* __restrict__ W2,
                        const float* __restrict__ in0, const float* __restrict__ in1,
                        uint4* __restrict__ Wt, unsigned* __restrict__ x_bf) {
    int bx = blockIdx.x;
    if (bx < 8192) {
        const int tid  = threadIdx.x;
        const int lane = tid & 63, wave = tid >> 6;
        const unsigned f = bx * 4 + wave;
        const unsigned n16 = f >> 11;
        const unsigned kchunk = (f >> 1) & 1023u;
        const unsigned kst = f & 1u;
        const unsigned n = n16 * 16 + (lane & 15);
        const unsigned K = kchunk * 64 + kst * 32 + (lane >> 4) * 8;
        const float* src = (n < 128 ? W1 + ((size_t)n << 16)
                                    : W2 + ((size_t)(n - 128) << 16)) + K;
        float4 a = ((const float4*)src)[0];
        float4 b = ((const float4*)src)[1];
        uint4 o;
        o.x = pack2bf(a.x, a.y); o.y = pack2bf(a.z, a.w);
        o.z = pack2bf(b.x, b.y); o.w = pack2bf(b.z, b.w);
        Wt[(size_t)f * 64 + lane] = o;        // contiguous 1KB per wave
    } else {
        unsigned v = (bx - 8192) * 256 + threadIdx.x; // 262,144 units of 4 elems
        unsigned b = v >> 6;
        unsigned j4 = (v & 63u) * 4u;
        const float* src = (j4 < 128) ? (in0 + (size_t)b * 128 + j4)
                                      : (in1 + (size_t)b * 128 + (j4 - 128));
        float4 a = *(const float4*)src;
        uint2 o;
        o.x = pack2bf(a.x, a.y);
        o.y = pack2bf(a.z, a.w);
        ((uint2*)x_bf)[v] = o;
    }
}

// ---------------- main GEMM: 128x128 tile, split-K=8, barrier-free ----------
// grid 512: ks = bx&7 (XCD-pinned), nt = (bx>>3)&1, mt = bx>>4 (0..31).
// block 256 = 4 waves; wave w owns n-cols [w*32, w*32+32), all 128 m-rows.
__launch_bounds__(256, 2)
__global__ void gemm_p(const unsigned char* __restrict__ Wt,
                       const float* __restrict__ st0, const float* __restrict__ st1,
                       const __hip_bfloat16* __restrict__ x_bf,
                       float* __restrict__ Mpart) {
    const int bx = blockIdx.x;
    const int ks = bx & 7;                  // split-K slice, pinned per XCD
    const int nt = (bx >> 3) & 1;
    const int mt = bx >> 4;
    const int b0 = mt << 7, n0 = nt << 7;
    const int tid  = threadIdx.x;
    const int lane = tid & 63, wave = tid >> 6;
    const int l15 = lane & 15, l4 = lane >> 4;

    // s tile: [32 j][132 r] f32 (pad to 132 -> broadcast-clean)
    __shared__ __align__(16) float Sl[32 * 132];
    for (int idx = tid; idx < 4096; idx += 256) {
        int r = idx >> 5, j = idx & 31;
        int jg = ks * 32 + j;
        float v = (jg < 128) ? st0[(size_t)(b0 + r) * 128 + jg]
                             : st1[(size_t)(b0 + r) * 128 + (jg - 128)];
        Sl[j * 132 + r] = v;
    }
    __syncthreads();                        // the ONLY barrier

    // Wave-uniform Wt slice bases in SGPRs: n16(nf) = nt*8 + wave*2 + nf.
    const int n16_0 = __builtin_amdgcn_readfirstlane(nt * 8 + wave * 2 + 0);
    const int n16_1 = __builtin_amdgcn_readfirstlane(nt * 8 + wave * 2 + 1);
    const unsigned char* wb0 = Wt + ((size_t)n16_0 << 21);
    const unsigned char* wb1 = Wt + ((size_t)n16_1 << 21);

    f32x4 racc[8][2];
    #pragma unroll
    for (int mf = 0; mf < 8; ++mf)
        #pragma unroll
        for (int nf = 0; nf < 2; ++nf)
            racc[mf][nf] = (f32x4){0.f, 0.f, 0.f, 0.f};
    const f32x4 zacc = (f32x4){0.f, 0.f, 0.f, 0.f};

    bf8 a[8][2];                            // x A-frags, reloaded per quadrant
    bf8 buf[2][2][2];                       // [ping][nf][kst] B-frags

    // Running within-slice byte offset: vo(q,j) = lane*16 + ks*262144 + q*2048
    //                                           + j*8192   (kst*1024 in imm)
    unsigned vo = (unsigned)lane * 16u + (unsigned)ks * 262144u;

    for (int q = 0; q < 4; ++q) {
        // A-frags for this x-quadrant (x_bf row-major, L2-resident)
        #pragma unroll
        for (int mf = 0; mf < 8; ++mf) {
            const __hip_bfloat16* xp =
                x_bf + (size_t)((b0 + mf * 16 + l15) * 256 + q * 64 + l4 * 8);
            a[mf][0] = *(const bf8*)(xp);
            a[mf][1] = *(const bf8*)(xp + 32);
        }
        // peel j=0 B-frags (one exposed latency per 32 chunks)
        buf[0][0][0] = *(const bf8*)(wb0 + vo);
        buf[0][0][1] = *(const bf8*)(wb0 + vo + 1024);
        buf[0][1][0] = *(const bf8*)(wb1 + vo);
        buf[0][1][1] = *(const bf8*)(wb1 + vo + 1024);
        vo += 8192;                          // -> prefetch target j=1

        const float* svp = Sl + l4 * 4;      // s broadcast ptr, +132/chunk

        for (int jb = 0; jb < 4; ++jb) {
            #pragma unroll
            for (int jj = 0; jj < 8; ++jj) {
                const int pp = jj & 1;       // compile-time ping-pong
                // prefetch next chunk's B-frags (last chunk of q prefetches
                // 2KB past the j-range: lands in valid ws, overwritten unused)
                buf[pp ^ 1][0][0] = *(const bf8*)(wb0 + vo);
                buf[pp ^ 1][0][1] = *(const bf8*)(wb0 + vo + 1024);
                buf[pp ^ 1][1][0] = *(const bf8*)(wb1 + vo);
                buf[pp ^ 1][1][1] = *(const bf8*)(wb1 + vo + 1024);
                vo += 8192;
                // s broadcast values for this j (imm-folded mf*64B)
                f32x4 sv[8];
                #pragma unroll
                for (int mf = 0; mf < 8; ++mf)
                    sv[mf] = *(const f32x4*)(svp + mf * 16);
                svp += 132;
                // 32 MFMA + 16 pk-fma, distance-1 software pipeline over
                // named registers mA/mB (flat macro sequence, fully static).
                {
                    f32x4 mA, mB;
#define PAIR_(MF, NF, MD) \
    MD = __builtin_amdgcn_mfma_f32_16x16x32_bf16(a[MF][0], buf[pp][NF][0], zacc, 0, 0, 0); \
    MD = __builtin_amdgcn_mfma_f32_16x16x32_bf16(a[MF][1], buf[pp][NF][1], MD, 0, 0, 0);
#define ACC_(MF, NF, MS) racc[MF][NF] += sv[MF] * MS;
                    PAIR_(0, 0, mA)
                    PAIR_(1, 0, mB)  ACC_(0, 0, mA)
                    PAIR_(2, 0, mA)  ACC_(1, 0, mB)
                    PAIR_(3, 0, mB)  ACC_(2, 0, mA)
                    PAIR_(4, 0, mA)  ACC_(3, 0, mB)
                    PAIR_(5, 0, mB)  ACC_(4, 0, mA)
                    PAIR_(6, 0, mA)  ACC_(5, 0, mB)
                    PAIR_(7, 0, mB)  ACC_(6, 0, mA)
                    PAIR_(0, 1, mA)  ACC_(7, 0, mB)
                    PAIR_(1, 1, mB)  ACC_(0, 1, mA)
                    PAIR_(2, 1, mA)  ACC_(1, 1, mB)
                    PAIR_(3, 1, mB)  ACC_(2, 1, mA)
                    PAIR_(4, 1, mA)  ACC_(3, 1, mB)
                    PAIR_(5, 1, mB)  ACC_(4, 1, mA)
                    PAIR_(6, 1, mA)  ACC_(5, 1, mB)
                    PAIR_(7, 1, mB)  ACC_(6, 1, mA)
                                     ACC_(7, 1, mB)
#undef PAIR_
#undef ACC_
                }
            }
        }
        vo += 2048 - 33 * 8192;              // rewind to (q+1, j=0)
    }

    // split-K partial stores (regular stores: producer->consumer coherence)
    float* mp = Mpart + ((size_t)ks << 20);
    #pragma unroll
    for (int mf = 0; mf < 8; ++mf)
        #pragma unroll
        for (int nf = 0; nf < 2; ++nf) {
            int b = b0 + mf * 16 + l4 * 4;
            int n = n0 + wave * 32 + nf * 16 + l15;
            #pragma unroll
            for (int r = 0; r < 4; ++r)
                mp[(size_t)(b + r) * 256 + n] = racc[mf][nf][r];
        }
}

// ---------------- epilogue: reduce split-K, s@W3, activations, blend --------
__global__ void epilogue(const float* __restrict__ st0, const float* __restrict__ st1,
                         const float* __restrict__ b1, const float* __restrict__ b2,
                         const float* __restrict__ W3, const float* __restrict__ Mpart,
                         float* __restrict__ out) {
    const int tid = threadIdx.x;
    const int h = tid & 127, rg = tid >> 7;          // rg in {0,1}
    const int bbase = blockIdx.x * 4;                // 4 rows per block
    __shared__ float srow[4][256];
    #pragma unroll
    for (int i = 0; i < 4; ++i) {
        int idx = i * 256 + tid;
        int r = idx >> 8, j = idx & 255;
        float v = (j < 128) ? st0[(size_t)(bbase + r) * 128 + j]
                            : st1[(size_t)(bbase + r) * 128 + (j - 128)];
        srow[r][j] = v;
    }
    __syncthreads();
    float acc0 = 0.f, acc1 = 0.f;
    #pragma unroll 8
    for (int j = 0; j < 256; ++j) {
        float w = W3[j * 128 + h];
        acc0 += srow[rg][j] * w;
        acc1 += srow[rg + 2][j] * w;
    }
    float accs[2] = {acc0, acc1};
    float bb1 = b1[h], bb2 = b2[h];
    #pragma unroll
    for (int i = 0; i < 2; ++i) {
        int b = bbase + rg + i * 2;
        float m1 = 0.f, m2 = 0.f;
        #pragma unroll
        for (int k = 0; k < 8; ++k) {
            m1 += Mpart[((size_t)k << 20) + (size_t)b * 256 + h];
            m2 += Mpart[((size_t)k << 20) + (size_t)b * 256 + 128 + h];
        }
        float u = 1.0f / (1.0f + expf(-(m2 + bb2)));
        float t = tanhf(m1 + bb1);
        out[(size_t)b * 128 + h] = u * t + (1.0f - u) * accs[i];
    }
}

extern "C" void kernel_launch(void* const* d_in, const int* in_sizes, int n_in,
                              void* d_out, int out_size, void* d_ws, size_t ws_size,
                              hipStream_t stream) {
    const float* in0 = (const float*)d_in[0];
    const float* in1 = (const float*)d_in[1];
    const float* st0 = (const float*)d_in[2];
    const float* st1 = (const float*)d_in[3];
    const float* W1  = (const float*)d_in[4];
    const float* b1  = (const float*)d_in[5];
    const float* W2  = (const float*)d_in[6];
    const float* b2  = (const float*)d_in[7];
    const float* W3  = (const float*)d_in[8];
    float* out = (float*)d_out;
    char* ws = (char*)d_ws;

    unsigned char* Wt   = (unsigned char*)(ws + WT_OFF);
    unsigned*      x_bf = (unsigned*)(ws + XBF_OFF);
    float*         Mp   = (float*)(ws + MP_OFF);

    prep_wx<<<9216, 256, 0, stream>>>(W1, W2, in0, in1, (uint4*)Wt, x_bf);
    gemm_p<<<512, 256, 0, stream>>>(Wt, st0, st1, (const __hip_bfloat16*)x_bf, Mp);
    epilogue<<<1024, 256, 0, stream>>>(st0, st1, b1, b2, W3, Mp, out);
}

// Round 8
// 256.596 us; speedup vs baseline: 1.4942x; 1.0085x over previous
//
#include <hip/hip_runtime.h>
#include <hip/hip_bf16.h>
#include <stdint.h>

// ---------------------------------------------------------------------------
// TensorizedGRU: m[b,l] = sum_{j,k} s[b,j] x[b,k] W[l,j,k]  (l in [0,256): W1||W2)
// R17 = R16 gemm + two independent levers:
//  LEVER 1 (gemm): s_setprio(1) around the MFMA cluster, (0) elsewhere.
//    Evidence: round = MFMA-phase(1240cyc) + VALU-phase(~670cyc) SERIALIZED
//    (util 46% across R9..R16; latency/occupancy/LDS theories all falsified).
//    The 2 co-resident blocks' waves share a SIMD with NO common barrier ->
//    anti-phase is reachable; setprio makes in-phase unstable (leader
//    monopolizes issue during MFMA, SIMD-mate slips into anti-phase). T5's
//    regime: null on barrier-locked loops (m190), pays on free-running ones.
//  LEVER 2 (prep): LDS-bounce tiled transpose. Old W-read = 16x128B gather
//    at EXACT 256KB stride (DRAM channel-aliasing suspect; residual ~118us
//    persists since the pre-R9 ~110us producer). New: 2KB-contiguous reads,
//    XOR-swizzled 16KB LDS tile, 1KB-contiguous frag writes. Wt layout is
//    byte-identical to R12/R16 -> gemm unaffected. Attribution: dGemm from
//    counters, dResidual = dTotal - dGemm.
// ws layout:
//   Wt   bf16 [256][65536]  @ 0          (33,554,432 B)  fragment-ordered
//   x_bf bf16 [4096][256]   @ 32MiB+2MiB ( 2,097,152 B)
//   Mpart f32 [8][4096][256]@ +2MiB      (33,554,432 B)
// ---------------------------------------------------------------------------

typedef short bf8 __attribute__((ext_vector_type(8)));   // 8 bf16 = 4 VGPRs
typedef float f32x4 __attribute__((ext_vector_type(4)));

static constexpr size_t WT_OFF  = 0;
static constexpr size_t XBF_OFF = 33554432 + 2097152;
static constexpr size_t MP_OFF  = XBF_OFF + 2097152;

// round-to-nearest-even f32 -> bf16 (finite inputs only)
__device__ __forceinline__ unsigned f2bf(float f) {
    unsigned u = __builtin_bit_cast(unsigned, f);
    return (u + 0x7fffu + ((u >> 16) & 1u)) >> 16;
}
__device__ __forceinline__ unsigned pack2bf(float a, float b) {
    return f2bf(a) | (f2bf(b) << 16);
}

// ---------------- prep: tiled transpose via LDS (coalesced both sides) -----
// Blocks 0..2047: (n16 = bx>>7, g = bx&127). Source = W rows
//   [n16*16, n16*16+16) x cols [g*512, (g+1)*512) f32  (2KB-contig reads).
// Dest = frags f = (n16*1024 + g*8 + kl)*2 + kst, kl in [0,8), kst in {0,1}
//   -> 16KB contiguous at Wt + (n16*1024+g*8)*2048 (1KB-contig writes).
// Frag content (16x16x32 B-op): lane l holds
//   W_bf[n16*16+(l&15)][kchunk*64 + kst*32 + (l>>4)*8 ..+8)   [same as R12]
// LDS: [16 r][512 k] bf16, byte ^= (r&7)<<4 (write-side 2-way free; read
// lands on the 8-cyc b128 floor, conflict-free).
// Blocks 2048..3071: x = in0||in1 -> bf16 (row-major [4096][256]).
__global__ void prep_wx(const float* __restrict__ W1, const float* __restrict__ W2,
                        const float* __restrict__ in0, const float* __restrict__ in1,
                        uint4* __restrict__ Wt, unsigned* __restrict__ x_bf) {
    int bx = blockIdx.x;
    if (bx < 2048) {
        const int tid = threadIdx.x;
        const int n16 = bx >> 7;
        const int g   = bx & 127;
        __shared__ __align__(16) unsigned short lds[16 * 512];   // 16 KiB
        const float* base = (n16 < 8)
            ? (W1 + ((size_t)(n16 * 16) << 16))
            : (W2 + ((size_t)((n16 - 8) * 16) << 16));
        // phase 1: 16 rows x 512 f32 -> bf16 -> swizzled LDS
        #pragma unroll
        for (int t = 0; t < 8; ++t) {
            int idx = t * 256 + tid;
            int r  = idx >> 7;            // 0..15
            int c4 = idx & 127;           // 0..127 (float4 units)
            float4 v = *(const float4*)(base + ((size_t)r << 16) + g * 512 + c4 * 4);
            uint2 o;
            o.x = pack2bf(v.x, v.y);
            o.y = pack2bf(v.z, v.w);
            unsigned byte = (unsigned)(r * 1024 + c4 * 8) ^ (unsigned)((r & 7) << 4);
            *(uint2*)((char*)lds + byte) = o;
        }
        __syncthreads();
        // phase 2: gather frags from LDS, stream 16KB contiguous to Wt
        uint4* outp = Wt + (size_t)(n16 * 1024 + g * 8) * 2 * 64;
        #pragma unroll
        for (int t = 0; t < 4; ++t) {
            int idx  = t * 256 + tid;
            int fl   = idx >> 6;          // 0..15 = kl*2 + kst
            int lane = idx & 63;
            int r = lane & 15;
            int k = (fl >> 1) * 64 + (fl & 1) * 32 + (lane >> 4) * 8;
            unsigned byte = (unsigned)(r * 1024 + k * 2) ^ (unsigned)((r & 7) << 4);
            outp[fl * 64 + lane] = *(const uint4*)((const char*)lds + byte);
        }
    } else {
        unsigned v = (bx - 2048) * 256 + threadIdx.x; // 262,144 units of 4 elems
        unsigned b = v >> 6;
        unsigned j4 = (v & 63u) * 4u;
        const float* src = (j4 < 128) ? (in0 + (size_t)b * 128 + j4)
                                      : (in1 + (size_t)b * 128 + (j4 - 128));
        float4 a = *(const float4*)src;
        uint2 o;
        o.x = pack2bf(a.x, a.y);
        o.y = pack2bf(a.z, a.w);
        ((uint2*)x_bf)[v] = o;
    }
}

// ---------------- main GEMM: 128x128 tile, split-K=8, barrier-free ----------
// grid 512: ks = bx&7 (XCD-pinned), nt = (bx>>3)&1, mt = bx>>4 (0..31).
// block 256 = 4 waves; wave w owns n-cols [w*32, w*32+32), all 128 m-rows.
__launch_bounds__(256, 2)
__global__ void gemm_p(const unsigned char* __restrict__ Wt,
                       const float* __restrict__ st0, const float* __restrict__ st1,
                       const __hip_bfloat16* __restrict__ x_bf,
                       float* __restrict__ Mpart) {
    const int bx = blockIdx.x;
    const int ks = bx & 7;                  // split-K slice, pinned per XCD
    const int nt = (bx >> 3) & 1;
    const int mt = bx >> 4;
    const int b0 = mt << 7, n0 = nt << 7;
    const int tid  = threadIdx.x;
    const int lane = tid & 63, wave = tid >> 6;
    const int l15 = lane & 15, l4 = lane >> 4;

    // s tile: [32 j][132 r] f32 (pad to 132 -> broadcast-clean)
    __shared__ __align__(16) float Sl[32 * 132];
    for (int idx = tid; idx < 4096; idx += 256) {
        int r = idx >> 5, j = idx & 31;
        int jg = ks * 32 + j;
        float v = (jg < 128) ? st0[(size_t)(b0 + r) * 128 + jg]
                             : st1[(size_t)(b0 + r) * 128 + (jg - 128)];
        Sl[j * 132 + r] = v;
    }
    __syncthreads();                        // the ONLY barrier

    // Wave-uniform Wt slice bases in SGPRs: n16(nf) = nt*8 + wave*2 + nf.
    const int n16_0 = __builtin_amdgcn_readfirstlane(nt * 8 + wave * 2 + 0);
    const int n16_1 = __builtin_amdgcn_readfirstlane(nt * 8 + wave * 2 + 1);
    const unsigned char* wb0 = Wt + ((size_t)n16_0 << 21);
    const unsigned char* wb1 = Wt + ((size_t)n16_1 << 21);

    f32x4 racc[8][2];
    #pragma unroll
    for (int mf = 0; mf < 8; ++mf)
        #pragma unroll
        for (int nf = 0; nf < 2; ++nf)
            racc[mf][nf] = (f32x4){0.f, 0.f, 0.f, 0.f};
    const f32x4 zacc = (f32x4){0.f, 0.f, 0.f, 0.f};

    bf8 a[8][2];                            // x A-frags, reloaded per quadrant
    bf8 buf[2][2][2];                       // [ping][nf][kst] B-frags

    // Running within-slice byte offset: vo(q,j) = lane*16 + ks*262144 + q*2048
    //                                           + j*8192   (kst*1024 in imm)
    unsigned vo = (unsigned)lane * 16u + (unsigned)ks * 262144u;

    for (int q = 0; q < 4; ++q) {
        // A-frags for this x-quadrant (x_bf row-major, L2-resident)
        #pragma unroll
        for (int mf = 0; mf < 8; ++mf) {
            const __hip_bfloat16* xp =
                x_bf + (size_t)((b0 + mf * 16 + l15) * 256 + q * 64 + l4 * 8);
            a[mf][0] = *(const bf8*)(xp);
            a[mf][1] = *(const bf8*)(xp + 32);
        }
        // peel j=0 B-frags (one exposed latency per 32 chunks)
        buf[0][0][0] = *(const bf8*)(wb0 + vo);
        buf[0][0][1] = *(const bf8*)(wb0 + vo + 1024);
        buf[0][1][0] = *(const bf8*)(wb1 + vo);
        buf[0][1][1] = *(const bf8*)(wb1 + vo + 1024);
        vo += 8192;                          // -> prefetch target j=1

        const float* svp = Sl + l4 * 4;      // s broadcast ptr, +132/chunk

        for (int jb = 0; jb < 4; ++jb) {
            #pragma unroll
            for (int jj = 0; jj < 8; ++jj) {
                const int pp = jj & 1;       // compile-time ping-pong
                // prefetch next chunk's B-frags (last chunk of q prefetches
                // 2KB past the j-range: lands in valid ws, overwritten unused)
                buf[pp ^ 1][0][0] = *(const bf8*)(wb0 + vo);
                buf[pp ^ 1][0][1] = *(const bf8*)(wb0 + vo + 1024);
                buf[pp ^ 1][1][0] = *(const bf8*)(wb1 + vo);
                buf[pp ^ 1][1][1] = *(const bf8*)(wb1 + vo + 1024);
                vo += 8192;
                // s broadcast values for this j (imm-folded mf*64B)
                f32x4 sv[8];
                #pragma unroll
                for (int mf = 0; mf < 8; ++mf)
                    sv[mf] = *(const f32x4*)(svp + mf * 16);
                svp += 132;
                // MFMA cluster at raised priority: makes in-phase waves
                // unstable -> SIMD-mate slips into anti-phase, its VALU
                // phase hides under our MFMA phase (T5 mechanism).
                __builtin_amdgcn_s_setprio(1);
                {
                    f32x4 mA, mB;
#define PAIR_(MF, NF, MD) \
    MD = __builtin_amdgcn_mfma_f32_16x16x32_bf16(a[MF][0], buf[pp][NF][0], zacc, 0, 0, 0); \
    MD = __builtin_amdgcn_mfma_f32_16x16x32_bf16(a[MF][1], buf[pp][NF][1], MD, 0, 0, 0);
#define ACC_(MF, NF, MS) racc[MF][NF] += sv[MF] * MS;
                    PAIR_(0, 0, mA)
                    PAIR_(1, 0, mB)  ACC_(0, 0, mA)
                    PAIR_(2, 0, mA)  ACC_(1, 0, mB)
                    PAIR_(3, 0, mB)  ACC_(2, 0, mA)
                    PAIR_(4, 0, mA)  ACC_(3, 0, mB)
                    PAIR_(5, 0, mB)  ACC_(4, 0, mA)
                    PAIR_(6, 0, mA)  ACC_(5, 0, mB)
                    PAIR_(7, 0, mB)  ACC_(6, 0, mA)
                    PAIR_(0, 1, mA)  ACC_(7, 0, mB)
                    PAIR_(1, 1, mB)  ACC_(0, 1, mA)
                    PAIR_(2, 1, mA)  ACC_(1, 1, mB)
                    PAIR_(3, 1, mB)  ACC_(2, 1, mA)
                    PAIR_(4, 1, mA)  ACC_(3, 1, mB)
                    PAIR_(5, 1, mB)  ACC_(4, 1, mA)
                    PAIR_(6, 1, mA)  ACC_(5, 1, mB)
                    PAIR_(7, 1, mB)  ACC_(6, 1, mA)
                                     ACC_(7, 1, mB)
#undef PAIR_
#undef ACC_
                }
                __builtin_amdgcn_s_setprio(0);
            }
        }
        vo += 2048 - 33 * 8192;              // rewind to (q+1, j=0)
    }

    // split-K partial stores (regular stores: producer->consumer coherence)
    float* mp = Mpart + ((size_t)ks << 20);
    #pragma unroll
    for (int mf = 0; mf < 8; ++mf)
        #pragma unroll
        for (int nf = 0; nf < 2; ++nf) {
            int b = b0 + mf * 16 + l4 * 4;
            int n = n0 + wave * 32 + nf * 16 + l15;
            #pragma unroll
            for (int r = 0; r < 4; ++r)
                mp[(size_t)(b + r) * 256 + n] = racc[mf][nf][r];
        }
}

// ---------------- epilogue: reduce split-K, s@W3, activations, blend --------
__global__ void epilogue(const float* __restrict__ st0, const float* __restrict__ st1,
                         const float* __restrict__ b1, const float* __restrict__ b2,
                         const float* __restrict__ W3, const float* __restrict__ Mpart,
                         float* __restrict__ out) {
    const int tid = threadIdx.x;
    const int h = tid & 127, rg = tid >> 7;          // rg in {0,1}
    const int bbase = blockIdx.x * 4;                // 4 rows per block
    __shared__ float srow[4][256];
    #pragma unroll
    for (int i = 0; i < 4; ++i) {
        int idx = i * 256 + tid;
        int r = idx >> 8, j = idx & 255;
        float v = (j < 128) ? st0[(size_t)(bbase + r) * 128 + j]
                            : st1[(size_t)(bbase + r) * 128 + (j - 128)];
        srow[r][j] = v;
    }
    __syncthreads();
    float acc0 = 0.f, acc1 = 0.f;
    #pragma unroll 8
    for (int j = 0; j < 256; ++j) {
        float w = W3[j * 128 + h];
        acc0 += srow[rg][j] * w;
        acc1 += srow[rg + 2][j] * w;
    }
    float accs[2] = {acc0, acc1};
    float bb1 = b1[h], bb2 = b2[h];
    #pragma unroll
    for (int i = 0; i < 2; ++i) {
        int b = bbase + rg + i * 2;
        float m1 = 0.f, m2 = 0.f;
        #pragma unroll
        for (int k = 0; k < 8; ++k) {
            m1 += Mpart[((size_t)k << 20) + (size_t)b * 256 + h];
            m2 += Mpart[((size_t)k << 20) + (size_t)b * 256 + 128 + h];
        }
        float u = 1.0f / (1.0f + expf(-(m2 + bb2)));
        float t = tanhf(m1 + bb1);
        out[(size_t)b * 128 + h] = u * t + (1.0f - u) * accs[i];
    }
}

extern "C" void kernel_launch(void* const* d_in, const int* in_sizes, int n_in,
                              void* d_out, int out_size, void* d_ws, size_t ws_size,
                              hipStream_t stream) {
    const float* in0 = (const float*)d_in[0];
    const float* in1 = (const float*)d_in[1];
    const float* st0 = (const float*)d_in[2];
    const float* st1 = (const float*)d_in[3];
    const float* W1  = (const float*)d_in[4];
    const float* b1  = (const float*)d_in[5];
    const float* W2  = (const float*)d_in[6];
    const float* b2  = (const float*)d_in[7];
    const float* W3  = (const float*)d_in[8];
    float* out = (float*)d_out;
    char* ws = (char*)d_ws;

    unsigned char* Wt   = (unsigned char*)(ws + WT_OFF);
    unsigned*      x_bf = (unsigned*)(ws + XBF_OFF);
    float*         Mp   = (float*)(ws + MP_OFF);

    prep_wx<<<3072, 256, 0, stream>>>(W1, W2, in0, in1, (uint4*)Wt, x_bf);
    gemm_p<<<512, 256, 0, stream>>>(Wt, st0, st1, (const __hip_bfloat16*)x_bf, Mp);
    epilogue<<<1024, 256, 0, stream>>>(st0, st1, b1, b2, W3, Mp, out);
}